// Round 6
// baseline (300.266 us; speedup 1.0000x reference)
//
#include <hip/hip_runtime.h>
#include <hip/hip_bf16.h>

constexpr int BB = 2;        // batch
constexpr int CC = 128;      // channels
constexpr int NN = 65536;    // H*W pixels
constexpr int MM = 1024;     // N / chunks
constexpr int LASTOFF = 63 * 1024;   // pixel offset of last chunk
constexpr float INV_T = 1.0f / 0.07f;
constexpr float L2E = 1.44269504088896340736f;  // log2(e)
constexpr float C2 = INV_T * L2E;               // /T and ln->log2 fold
// loss = accum_base2 / (count * L2E); count = B*chunks*M*(M+1) = 134348800
constexpr float SCALE = 1.0f / (134348800.0f * 1.44269504088896340736f);
constexpr float EPSN = 1e-12f;

typedef float f32x4 __attribute__((ext_vector_type(4)));
typedef short bf16x8 __attribute__((ext_vector_type(8)));

__device__ __forceinline__ uint pack_bf16(float a, float b) {
  __hip_bfloat16 ha = __float2bfloat16(a);
  __hip_bfloat16 hb = __float2bfloat16(b);
  ushort ua = *reinterpret_cast<ushort*>(&ha);
  ushort ub = *reinterpret_cast<ushort*>(&hb);
  return (uint)ua | ((uint)ub << 16);
}

// ---------------------------------------------------------------------------
// K1: normalize + transpose + bf16 for z2's last chunk (B side)
//     + per-label column-sum partials S_v = sum_{cl != v} col_n  (fp32 atomics).
__global__ __launch_bounds__(256) void k_r2(
    const float* __restrict__ z2, const int* __restrict__ lab,
    uint* __restrict__ r2n, float* __restrict__ Sv) {
  __shared__ float t2[64 * 129];
  __shared__ float part[8][65];
  __shared__ float inv2s[64];
  __shared__ int cls[64];
  const int b = blockIdx.y;
  const int pg = blockIdx.x * 64;          // within last chunk
  const int p0 = LASTOFF + pg;
  const int t = threadIdx.x;
  const int p2 = t & 31;
  const int q = t >> 5;
  const float* s2 = z2 + (size_t)b * CC * NN + p0 + 2 * p2;
  float a22 = 0.f, b22 = 0.f;
#pragma unroll
  for (int e = 0; e < 16; e++) {
    int c = e * 8 + q;
    float2 y = *reinterpret_cast<const float2*>(s2 + (size_t)c * NN);
    t2[(2 * p2) * 129 + c] = y.x;
    t2[(2 * p2 + 1) * 129 + c] = y.y;
    a22 += y.x * y.x;
    b22 += y.y * y.y;
  }
  part[q][2 * p2] = a22;
  part[q][2 * p2 + 1] = b22;
  __syncthreads();
  if (t < 64) {
    float s22 = 0.f;
#pragma unroll
    for (int qq = 0; qq < 8; qq++) s22 += part[qq][t];
    inv2s[t] = 1.0f / fmaxf(sqrtf(s22), EPSN);
    cls[t] = lab[(size_t)b * NN + p0 + t];
  }
  __syncthreads();
  const size_t obase = ((size_t)b * MM + pg) * 64;
#pragma unroll
  for (int e = 0; e < 16; e++) {
    int lin = e * 256 + t;
    int pp = lin >> 6;
    int cp = lin & 63;
    float i2 = inv2s[pp];
    float v0 = t2[pp * 129 + 2 * cp] * i2;
    float v1 = t2[pp * 129 + 2 * cp + 1] * i2;
    r2n[obase + (size_t)pp * 64 + cp] = pack_bf16(v0, v1);
  }
  // S_v partials: thread -> (channel c, pixel-half h)
  const int c = t & 127;
  const int h = t >> 7;
  float tot = 0.f, se0 = 0.f, se1 = 0.f, se2 = 0.f, se3 = 0.f, se4 = 0.f;
#pragma unroll
  for (int k = 0; k < 32; k++) {
    int pp = h * 32 + k;
    float val = t2[pp * 129 + c] * inv2s[pp];
    int lb = cls[pp];
    tot += val;
    se0 += (lb == 0) ? val : 0.f;
    se1 += (lb == 1) ? val : 0.f;
    se2 += (lb == 2) ? val : 0.f;
    se3 += (lb == 3) ? val : 0.f;
    se4 += (lb == 4) ? val : 0.f;
  }
  float* svb = Sv + b * 640 + c;
  atomicAdd(svb + 0 * 128, tot - se0);
  atomicAdd(svb + 1 * 128, tot - se1);
  atomicAdd(svb + 2 * 128, tot - se2);
  atomicAdd(svb + 3 * 128, tot - se3);
  atomicAdd(svb + 4 * 128, tot - se4);
}

// ---------------------------------------------------------------------------
// K2: pack S_v fp32 -> bf16 16-row extra B-tile (rows 5..15 zero).
__global__ void k_svpack(const float* __restrict__ Sv, ushort* __restrict__ r2x) {
  int i = blockIdx.x * 256 + threadIdx.x;  // 0..4095
  if (i >= BB * 16 * 128) return;
  int b = i >> 11, rr = (i >> 7) & 15, c = i & 127;
  float v = (rr < 5) ? Sv[b * 640 + rr * 128 + c] : 0.0f;
  __hip_bfloat16 h = __float2bfloat16(v);
  r2x[i] = *reinterpret_cast<ushort*>(&h);
}

// ---------------------------------------------------------------------------
// K3: FULLY FUSED. Per 128-px block: load z1+z2 tile once (the only HBM
// read), compute norms + pos in-block, stage RAW bf16 z1 in LDS, GEMM vs
// L2-resident B, defer row-normalization to the epilogue scale, finish the
// row softmax in-block (block owns all 1024 cols). 4 waves x 32 rows.
// C/D layout: col = lane&15, row = (lane>>4)*4 + reg.
__global__ __launch_bounds__(256, 4) void k_fused(
    const float* __restrict__ z1, const float* __restrict__ z2,
    const ushort* __restrict__ r2n, const ushort* __restrict__ r2x,
    const int* __restrict__ lab, float* __restrict__ accum) {
  __shared__ ushort At[128 * 130];        // raw z1 bf16 [c][px], 33,280 B
  __shared__ float part[3][4][129];       // norm partials, 6,192 B
  __shared__ float ivs[128];              // C2 / ||z1||
  __shared__ float poss[128];             // pos logit, base-2 domain
  const int b = blockIdx.y;
  const int px0 = blockIdx.x * 128;
  const int t = threadIdx.x;
  const size_t bN = (size_t)b * NN;

  // --- stage: load z1/z2 tile, accumulate norms, write raw bf16 z1 to LDS ---
  {
    const int g = t >> 6;          // channel group (32 ch)
    const int pr = 2 * (t & 63);   // pixel pair
    const float* p1 = z1 + (bN * CC) + px0 + pr;
    const float* p2 = z2 + (bN * CC) + px0 + pr;
    float s11a = 0.f, s22a = 0.f, s12a = 0.f;
    float s11b = 0.f, s22b = 0.f, s12b = 0.f;
#pragma unroll
    for (int e = 0; e < 32; e++) {
      const int c = g * 32 + e;
      float2 x = *reinterpret_cast<const float2*>(p1 + (size_t)c * NN);
      float2 y = *reinterpret_cast<const float2*>(p2 + (size_t)c * NN);
      *reinterpret_cast<uint*>(&At[c * 130 + pr]) = pack_bf16(x.x, x.y);
      s11a += x.x * x.x; s22a += y.x * y.x; s12a += x.x * y.x;
      s11b += x.y * x.y; s22b += y.y * y.y; s12b += x.y * y.y;
    }
    part[0][g][pr] = s11a; part[0][g][pr + 1] = s11b;
    part[1][g][pr] = s22a; part[1][g][pr + 1] = s22b;
    part[2][g][pr] = s12a; part[2][g][pr + 1] = s12b;
  }
  __syncthreads();
  if (t < 128) {
    float s11 = part[0][0][t] + part[0][1][t] + part[0][2][t] + part[0][3][t];
    float s22 = part[1][0][t] + part[1][1][t] + part[1][2][t] + part[1][3][t];
    float s12 = part[2][0][t] + part[2][1][t] + part[2][2][t] + part[2][3][t];
    float i1 = 1.0f / fmaxf(sqrtf(s11), EPSN);
    float i2 = 1.0f / fmaxf(sqrtf(s22), EPSN);
    ivs[t] = i1 * C2;
    poss[t] = s12 * i1 * i2 * C2;
  }
  __syncthreads();

  // --- GEMM phase: wave w owns rows [w*32, w*32+32) x all 1024 cols ---
  const int w = t >> 6;
  const int lane = t & 63;
  const int r = lane & 15;
  const int kg = lane >> 4;
  const int wrow0 = w * 32;

  bf16x8 av[2][4];
#pragma unroll
  for (int g = 0; g < 2; g++)
#pragma unroll
    for (int kk = 0; kk < 4; kk++) {
      bf16x8 tv;
#pragma unroll
      for (int j = 0; j < 8; j++)
        tv[j] = (short)At[(kg * 8 + kk * 32 + j) * 130 + wrow0 + g * 16 + r];
      av[g][kk] = tv;
    }

  int rl[8];
  float ivr[8];
#pragma unroll
  for (int g = 0; g < 2; g++)
#pragma unroll
    for (int i = 0; i < 4; i++) {
      const int sl = g * 4 + i;
      const int rowl = wrow0 + g * 16 + kg * 4 + i;
      rl[sl] = lab[bN + px0 + rowl];
      ivr[sl] = ivs[rowl];
    }

  float sAcc[8];
#pragma unroll
  for (int s = 0; s < 8; s++) sAcc[s] = 0.f;

  const ushort* Bbase = r2n + (size_t)b * MM * CC;
  const int* clbase = lab + bN + LASTOFF;

#pragma unroll 2
  for (int ch = 0; ch < 16; ch++) {
    const int n0 = ch * 64;
#pragma unroll
    for (int tt = 0; tt < 4; tt++) {
      const ushort* Bt = Bbase + (size_t)(n0 + tt * 16 + r) * CC + kg * 8;
      bf16x8 bv0 = *reinterpret_cast<const bf16x8*>(Bt);
      bf16x8 bv1 = *reinterpret_cast<const bf16x8*>(Bt + 32);
      bf16x8 bv2 = *reinterpret_cast<const bf16x8*>(Bt + 64);
      bf16x8 bv3 = *reinterpret_cast<const bf16x8*>(Bt + 96);
      int cl = clbase[n0 + tt * 16 + r];
      f32x4 a0 = {0.f, 0.f, 0.f, 0.f};
      f32x4 a1 = {0.f, 0.f, 0.f, 0.f};
      a0 = __builtin_amdgcn_mfma_f32_16x16x32_bf16(av[0][0], bv0, a0, 0, 0, 0);
      a1 = __builtin_amdgcn_mfma_f32_16x16x32_bf16(av[1][0], bv0, a1, 0, 0, 0);
      a0 = __builtin_amdgcn_mfma_f32_16x16x32_bf16(av[0][1], bv1, a0, 0, 0, 0);
      a1 = __builtin_amdgcn_mfma_f32_16x16x32_bf16(av[1][1], bv1, a1, 0, 0, 0);
      a0 = __builtin_amdgcn_mfma_f32_16x16x32_bf16(av[0][2], bv2, a0, 0, 0, 0);
      a1 = __builtin_amdgcn_mfma_f32_16x16x32_bf16(av[1][2], bv2, a1, 0, 0, 0);
      a0 = __builtin_amdgcn_mfma_f32_16x16x32_bf16(av[0][3], bv3, a0, 0, 0, 0);
      a1 = __builtin_amdgcn_mfma_f32_16x16x32_bf16(av[1][3], bv3, a1, 0, 0, 0);
      // deferred normalization: logit*C2 = raw_dot * ivr; masked -> exp2(0)=1
#pragma unroll
      for (int i = 0; i < 4; i++) {
        float x0 = (rl[i] != cl) ? a0[i] * ivr[i] : 0.0f;
        float x1 = (rl[4 + i] != cl) ? a1[i] * ivr[4 + i] : 0.0f;
        sAcc[i] += __builtin_amdgcn_exp2f(x0);
        sAcc[4 + i] += __builtin_amdgcn_exp2f(x1);
      }
    }
  }

  // x_row = ivr * dot(a_raw, S_rl) via the 16-col S_v tile
  float xsel[8];
  {
    const ushort* Bx = r2x + (size_t)b * 16 * CC + (size_t)r * CC + kg * 8;
    bf16x8 bx0 = *reinterpret_cast<const bf16x8*>(Bx);
    bf16x8 bx1 = *reinterpret_cast<const bf16x8*>(Bx + 32);
    bf16x8 bx2 = *reinterpret_cast<const bf16x8*>(Bx + 64);
    bf16x8 bx3 = *reinterpret_cast<const bf16x8*>(Bx + 96);
#pragma unroll
    for (int g = 0; g < 2; g++) {
      f32x4 ax = {0.f, 0.f, 0.f, 0.f};
      ax = __builtin_amdgcn_mfma_f32_16x16x32_bf16(av[g][0], bx0, ax, 0, 0, 0);
      ax = __builtin_amdgcn_mfma_f32_16x16x32_bf16(av[g][1], bx1, ax, 0, 0, 0);
      ax = __builtin_amdgcn_mfma_f32_16x16x32_bf16(av[g][2], bx2, ax, 0, 0, 0);
      ax = __builtin_amdgcn_mfma_f32_16x16x32_bf16(av[g][3], bx3, ax, 0, 0, 0);
#pragma unroll
      for (int i = 0; i < 4; i++)
        xsel[g * 4 + i] = __shfl(ax[i], (lane & 48) | rl[g * 4 + i]);
    }
  }

  // reduce sAcc across the 16 col-lanes sharing each row
#pragma unroll
  for (int d = 1; d < 16; d <<= 1)
#pragma unroll
    for (int s = 0; s < 8; s++) sAcc[s] += __shfl_xor(sAcc[s], d);

  float tv = 0.f;
  if (r == 0) {
#pragma unroll
    for (int g = 0; g < 2; g++)
#pragma unroll
      for (int i = 0; i < 4; i++) {
        const int sl = g * 4 + i;
        const int rowl = wrow0 + g * 16 + kg * 4 + i;
        float pv = poss[rowl];
        float s = sAcc[sl] + __builtin_amdgcn_exp2f(pv);
        float x = xsel[sl] * ivr[sl] + pv;
        tv += 1025.0f * __log2f(s) - x;
      }
  }
  tv += __shfl_xor(tv, 16);
  tv += __shfl_xor(tv, 32);
  if (lane == 0) atomicAdd(accum, tv);
}

// ---------------------------------------------------------------------------
__global__ void k_scale(const float* __restrict__ accum, float* __restrict__ out) {
  out[0] = accum[0] * SCALE;
}

// ---------------------------------------------------------------------------
extern "C" void kernel_launch(void* const* d_in, const int* in_sizes, int n_in,
                              void* d_out, int out_size, void* d_ws, size_t ws_size,
                              hipStream_t stream) {
  const float* z1 = (const float*)d_in[0];
  const float* z2 = (const float*)d_in[1];
  const int* lab = (const int*)d_in[2];

  char* ws = (char*)d_ws;
  uint* r2n   = (uint*)ws;                      // B*M*C bf16  = 524,288 B
  ushort* r2x = (ushort*)(ws + 524288);         // B*16*C bf16 =   8,192 B
  float* Sv   = (float*)(ws + 532480);          // B*5*128 f32 =   5,120 B
  float* accum = (float*)(ws + 537600);         //                     4 B

  hipMemsetAsync(ws + 532480, 0, 5124, stream);  // Sv + accum

  k_r2<<<dim3(MM / 64, BB), 256, 0, stream>>>(z2, lab, r2n, Sv);
  k_svpack<<<dim3(16), 256, 0, stream>>>(Sv, r2x);
  k_fused<<<dim3(NN / 128, BB), 256, 0, stream>>>(
      z1, z2, (const ushort*)r2n, r2x, lab, accum);
  k_scale<<<1, 1, 0, stream>>>(accum, (float*)d_out);
}